// Round 8
// baseline (16.336 us; speedup 1.0000x reference)
//
#include <hip/hip_runtime.h>

// NAM inference: B=16384 rows, F=64 features, U=64 units per FeatureNN.
// fnn[b,f] = sum_u clamp((x[b,f]-eb[f])*exp(w[f,u]),0,1)*lw[f,u] + lb[f]
// out[b]   = sum_f fnn[b,f] + bias
// I/O contract (HW-verified round 5): fp32 inputs, dict order;
// d_out fp32 = [out(16384) | fnn(16384x64 row-major)].
//
// Structure: lane = feature. Each lane holds its feature's entire weight
// columns in REGISTERS (ew[64], lw[64], exp pre-applied) -> the u-loop is
// pure VALU (mul + v_med3 + fma), no LDS, no per-iteration memory.
// Each wave owns 8 rows (4 in flight for ILP). x/fnn accesses are
// perfectly coalesced b32. Row-sum = 6-step shfl_xor butterfly.
// R7 bug fixed: grid must supply 2048 waves (512 blocks x 4 waves x 8 rows).

#define NB 16384
#define NF 64
#define NU 64

__global__ __launch_bounds__(256, 2) void nam_reg(
    const float* __restrict__ x,
    const float* __restrict__ exu_w,
    const float* __restrict__ exu_b,
    const float* __restrict__ lin_w,
    const float* __restrict__ lin_b,
    const float* __restrict__ bias,
    float* __restrict__ out,
    float* __restrict__ fnn) {

    const int lane = threadIdx.x & 63;
    const int wid  = (blockIdx.x * 256 + threadIdx.x) >> 6;   // 0..2047

    const float eb = exu_b[lane];
    const float lb = lin_b[lane];
    const float b0 = bias[0];

    // Load this lane's feature column of both weight tables into registers.
    // Fully-unrolled static indexing keeps ew/lw in VGPRs (128 regs).
    float ew[NU], lw[NU];
    {
        const float* ewp = exu_w + lane * NU;
        const float* lwp = lin_w + lane * NU;
#pragma unroll
        for (int k = 0; k < NU / 4; ++k) {
            float4 a = *(const float4*)(ewp + 4 * k);
            float4 b = *(const float4*)(lwp + 4 * k);
            ew[4*k+0] = a.x; ew[4*k+1] = a.y; ew[4*k+2] = a.z; ew[4*k+3] = a.w;
            lw[4*k+0] = b.x; lw[4*k+1] = b.y; lw[4*k+2] = b.z; lw[4*k+3] = b.w;
        }
    }
#pragma unroll
    for (int u = 0; u < NU; ++u) ew[u] = __expf(ew[u]);

    const int rbase = wid * 8;    // 2048 waves x 8 rows = 16384, uniform
#pragma unroll
    for (int rq = 0; rq < 2; ++rq) {
        const int r = rbase + rq * 4;

        // 4 rows in flight; coalesced b32 loads (lane = column).
        float xv0 = x[(size_t)(r + 0) * NF + lane] - eb;
        float xv1 = x[(size_t)(r + 1) * NF + lane] - eb;
        float xv2 = x[(size_t)(r + 2) * NF + lane] - eb;
        float xv3 = x[(size_t)(r + 3) * NF + lane] - eb;

        float a0 = 0.f, a1 = 0.f, a2 = 0.f, a3 = 0.f;
#pragma unroll
        for (int u = 0; u < NU; ++u) {
            const float e = ew[u], w = lw[u];
            a0 = __builtin_fmaf(__builtin_amdgcn_fmed3f(xv0 * e, 0.f, 1.f), w, a0);
            a1 = __builtin_fmaf(__builtin_amdgcn_fmed3f(xv1 * e, 0.f, 1.f), w, a1);
            a2 = __builtin_fmaf(__builtin_amdgcn_fmed3f(xv2 * e, 0.f, 1.f), w, a2);
            a3 = __builtin_fmaf(__builtin_amdgcn_fmed3f(xv3 * e, 0.f, 1.f), w, a3);
        }
        a0 += lb; a1 += lb; a2 += lb; a3 += lb;

        // Coalesced fnn stores.
        fnn[(size_t)(r + 0) * NF + lane] = a0;
        fnn[(size_t)(r + 1) * NF + lane] = a1;
        fnn[(size_t)(r + 2) * NF + lane] = a2;
        fnn[(size_t)(r + 3) * NF + lane] = a3;

        // Butterfly row-sums across the 64 lanes (all 4 rows at once).
        float s0 = a0, s1 = a1, s2 = a2, s3 = a3;
#pragma unroll
        for (int m = 1; m < 64; m <<= 1) {
            s0 += __shfl_xor(s0, m, 64);
            s1 += __shfl_xor(s1, m, 64);
            s2 += __shfl_xor(s2, m, 64);
            s3 += __shfl_xor(s3, m, 64);
        }
        if (lane == 0) {
            *(float4*)(out + r) = make_float4(s0 + b0, s1 + b0, s2 + b0, s3 + b0);
        }
    }
}

extern "C" void kernel_launch(void* const* d_in, const int* in_sizes, int n_in,
                              void* d_out, int out_size, void* d_ws, size_t ws_size,
                              hipStream_t stream) {
    const float* x     = (const float*)d_in[0];
    const float* exu_w = (const float*)d_in[1];
    const float* exu_b = (const float*)d_in[2];
    const float* lin_w = (const float*)d_in[3];
    const float* lin_b = (const float*)d_in[4];
    const float* bias  = (const float*)d_in[5];

    float* out = (float*)d_out;
    float* fnn = out + NB;

    // 2048 waves total: 512 blocks x 4 waves/block, 8 rows/wave = 16384 rows.
    nam_reg<<<dim3(512), dim3(256), 0, stream>>>(
        x, exu_w, exu_b, lin_w, lin_b, bias, out, fnn);
}

// Round 9
// 12.006 us; speedup vs baseline: 1.3607x; 1.3607x over previous
//
#include <hip/hip_runtime.h>

// NAM inference: B=16384 rows, F=64 features, U=64 units per FeatureNN.
// fnn[b,f] = sum_u clamp((x[b,f]-eb[f])*exp(w[f,u]),0,1)*lw[f,u] + lb[f]
// out[b]   = sum_f fnn[b,f] + bias
// I/O contract (HW-verified round 5): fp32 inputs, dict order;
// d_out fp32 = [out(16384) | fnn(16384x64 row-major)].
//
// R9 structure: coalesced global stage -> LDS transpose [f][65] (+1 pad:
// 2-way bank aliasing = free) -> per-lane register fill (lane = feature,
// ew/lw in 128 VGPRs, exp pre-applied) -> pure-VALU u-loop (mul+med3+fma,
// no memory ops). 8 rows/wave, 4 in flight. Butterfly shfl row-sums.
// Grid: 512 blocks x 256 threads = 2048 waves x 8 rows = 16384 rows exact.

#define NB 16384
#define NF 64
#define NU 64
#define LDS_P 65   // padded row stride in floats

__global__ __launch_bounds__(256, 2) void nam_reg(
    const float* __restrict__ x,
    const float* __restrict__ exu_w,
    const float* __restrict__ exu_b,
    const float* __restrict__ lin_w,
    const float* __restrict__ lin_b,
    const float* __restrict__ bias,
    float* __restrict__ out,
    float* __restrict__ fnn) {

    __shared__ float ews[NF * LDS_P];
    __shared__ float lws[NF * LDS_P];

    const int t = threadIdx.x;
    const int lane = t & 63;
    const int wid = (blockIdx.x * 256 + t) >> 6;   // 0..2047

    // --- Stage weights: coalesced float4 global loads, exp fused,
    // --- transposed write into padded LDS (2-way bank alias = free).
#pragma unroll
    for (int k = 0; k < 4; ++k) {
        int g = (k * 256 + t) * 4;              // 4 consecutive source floats
        float4 a = *(const float4*)(exu_w + g);
        float4 b = *(const float4*)(lin_w + g);
        int f = g >> 6;
        int u = g & 63;
        float* ep = &ews[f * LDS_P + u];
        float* lp = &lws[f * LDS_P + u];
        ep[0] = __expf(a.x); ep[1] = __expf(a.y);
        ep[2] = __expf(a.z); ep[3] = __expf(a.w);
        lp[0] = b.x; lp[1] = b.y; lp[2] = b.z; lp[3] = b.w;
    }

    const float eb = exu_b[lane];
    const float lb = lin_b[lane];
    const float b0 = bias[0];

    __syncthreads();

    // --- Fill this lane's feature column into registers (static indices ->
    // --- VGPRs). Column reads at stride 65: bank = (lane+u)%32 -> 2-way, free.
    float ew[NU], lw[NU];
#pragma unroll
    for (int u = 0; u < NU; ++u) {
        ew[u] = ews[lane * LDS_P + u];
        lw[u] = lws[lane * LDS_P + u];
    }

    const int rbase = wid * 8;
#pragma unroll
    for (int rq = 0; rq < 2; ++rq) {
        const int r = rbase + rq * 4;

        // 4 rows in flight; coalesced b32 loads (lane = column).
        float xv0 = x[(size_t)(r + 0) * NF + lane] - eb;
        float xv1 = x[(size_t)(r + 1) * NF + lane] - eb;
        float xv2 = x[(size_t)(r + 2) * NF + lane] - eb;
        float xv3 = x[(size_t)(r + 3) * NF + lane] - eb;

        float a0 = 0.f, a1 = 0.f, a2 = 0.f, a3 = 0.f;
#pragma unroll
        for (int u = 0; u < NU; ++u) {
            const float e = ew[u], w = lw[u];
            a0 = __builtin_fmaf(__builtin_amdgcn_fmed3f(xv0 * e, 0.f, 1.f), w, a0);
            a1 = __builtin_fmaf(__builtin_amdgcn_fmed3f(xv1 * e, 0.f, 1.f), w, a1);
            a2 = __builtin_fmaf(__builtin_amdgcn_fmed3f(xv2 * e, 0.f, 1.f), w, a2);
            a3 = __builtin_fmaf(__builtin_amdgcn_fmed3f(xv3 * e, 0.f, 1.f), w, a3);
        }
        a0 += lb; a1 += lb; a2 += lb; a3 += lb;

        // Coalesced fnn stores.
        fnn[(size_t)(r + 0) * NF + lane] = a0;
        fnn[(size_t)(r + 1) * NF + lane] = a1;
        fnn[(size_t)(r + 2) * NF + lane] = a2;
        fnn[(size_t)(r + 3) * NF + lane] = a3;

        // Butterfly row-sums across the 64 lanes (4 rows at once).
        float s0 = a0, s1 = a1, s2 = a2, s3 = a3;
#pragma unroll
        for (int m = 1; m < 64; m <<= 1) {
            s0 += __shfl_xor(s0, m, 64);
            s1 += __shfl_xor(s1, m, 64);
            s2 += __shfl_xor(s2, m, 64);
            s3 += __shfl_xor(s3, m, 64);
        }
        if (lane == 0) {
            *(float4*)(out + r) = make_float4(s0 + b0, s1 + b0, s2 + b0, s3 + b0);
        }
    }
}

extern "C" void kernel_launch(void* const* d_in, const int* in_sizes, int n_in,
                              void* d_out, int out_size, void* d_ws, size_t ws_size,
                              hipStream_t stream) {
    const float* x     = (const float*)d_in[0];
    const float* exu_w = (const float*)d_in[1];
    const float* exu_b = (const float*)d_in[2];
    const float* lin_w = (const float*)d_in[3];
    const float* lin_b = (const float*)d_in[4];
    const float* bias  = (const float*)d_in[5];

    float* out = (float*)d_out;
    float* fnn = out + NB;

    // 2048 waves total: 512 blocks x 4 waves/block, 8 rows/wave = 16384 rows.
    nam_reg<<<dim3(512), dim3(256), 0, stream>>>(
        x, exu_w, exu_b, lin_w, lin_b, bias, out, fnn);
}

// Round 10
// 11.239 us; speedup vs baseline: 1.4536x; 1.0683x over previous
//
#include <hip/hip_runtime.h>

// NAM inference: B=16384 rows, F=64 features, U=64 units per FeatureNN.
// fnn[b,f] = sum_u clamp((x[b,f]-eb[f])*exp(w[f,u]),0,1)*lw[f,u] + lb[f]
// out[b]   = sum_f fnn[b,f] + bias
// I/O contract (HW-verified round 5): fp32 inputs, dict order;
// d_out fp32 = [out(16384) | fnn(16384x64 row-major)].
//
// R10: (a) strength-reduced inner loop: with e=exp(w)>0,
//        clamp(x*e,0,1)*lw == p * med3(x,0,q),  p=lw*e, q=1/e
//      -> 2 VALU ops per (b,f,u) instead of 3.
//      (b) LDS pad 68 (16B-aligned rows) + explicit float4 LDS I/O ->
//        register fill is 32 ds_read_b128/wave instead of 128 ds_read_b32
//        (R9's pad 65 broke alignment and forced scalar reads).
//      (c) single 8-row pass per wave: one x-load batch, 8 fma chains.
// Grid: 512 blocks x 256 threads = 2048 waves x 8 rows = 16384 rows exact.

#define NB 16384
#define NF 64
#define NU 64
#define LDP 68   // padded LDS row stride (floats); rows 16B-aligned

__global__ __launch_bounds__(256, 2) void nam_reg(
    const float* __restrict__ x,
    const float* __restrict__ exu_w,
    const float* __restrict__ exu_b,
    const float* __restrict__ lin_w,
    const float* __restrict__ lin_b,
    const float* __restrict__ bias,
    float* __restrict__ out,
    float* __restrict__ fnn) {

    __shared__ float pws[NF * LDP];   // p = lw * exp(w)
    __shared__ float qws[NF * LDP];   // q = 1 / exp(w)

    const int t = threadIdx.x;
    const int lane = t & 63;
    const int wid = (blockIdx.x * 256 + t) >> 6;   // 0..2047

    // --- Stage: coalesced float4 loads of both tables (layout already [f][u]),
    // --- compute p,q, float4 stores to padded LDS (8-lane/4-bank minimal alias).
#pragma unroll
    for (int k = 0; k < 4; ++k) {
        int g = (k * 256 + t) * 4;              // 4 consecutive source floats
        float4 a = *(const float4*)(exu_w + g);
        float4 b = *(const float4*)(lin_w + g);
        int f = g >> 6;
        int u = g & 63;
        float e0 = __expf(a.x), e1 = __expf(a.y), e2 = __expf(a.z), e3 = __expf(a.w);
        *(float4*)&pws[f * LDP + u] = make_float4(b.x * e0, b.y * e1, b.z * e2, b.w * e3);
        *(float4*)&qws[f * LDP + u] = make_float4(__builtin_amdgcn_rcpf(e0),
                                                  __builtin_amdgcn_rcpf(e1),
                                                  __builtin_amdgcn_rcpf(e2),
                                                  __builtin_amdgcn_rcpf(e3));
    }

    const float eb = exu_b[lane];
    const float lb = lin_b[lane];
    const float b0 = bias[0];

    __syncthreads();

    // --- Fill this lane's feature row into registers: 16+16 ds_read_b128.
    float p[NU], q[NU];
    {
        const float4* pr = (const float4*)&pws[lane * LDP];
        const float4* qr = (const float4*)&qws[lane * LDP];
#pragma unroll
        for (int k = 0; k < NU / 4; ++k) {
            float4 pv = pr[k];
            float4 qv = qr[k];
            p[4*k+0] = pv.x; p[4*k+1] = pv.y; p[4*k+2] = pv.z; p[4*k+3] = pv.w;
            q[4*k+0] = qv.x; q[4*k+1] = qv.y; q[4*k+2] = qv.z; q[4*k+3] = qv.w;
        }
    }

    // --- 8 rows in one pass: coalesced x loads (lane = column), 8 chains.
    const int rbase = wid * 8;
    float xv[8], acc[8];
#pragma unroll
    for (int j = 0; j < 8; ++j) {
        xv[j] = x[(size_t)(rbase + j) * NF + lane] - eb;
        acc[j] = 0.0f;
    }

#pragma unroll
    for (int u = 0; u < NU; ++u) {
        const float pu = p[u], qu = q[u];
#pragma unroll
        for (int j = 0; j < 8; ++j) {
            acc[j] = __builtin_fmaf(pu, __builtin_amdgcn_fmed3f(xv[j], 0.f, qu), acc[j]);
        }
    }

    // --- Epilogue: + lin_b, coalesced fnn stores, butterfly row-sums, out.
    float s[8];
#pragma unroll
    for (int j = 0; j < 8; ++j) {
        float a = acc[j] + lb;
        fnn[(size_t)(rbase + j) * NF + lane] = a;
        s[j] = a;
    }
#pragma unroll
    for (int m = 1; m < 64; m <<= 1) {
#pragma unroll
        for (int j = 0; j < 8; ++j) s[j] += __shfl_xor(s[j], m, 64);
    }
    if (lane == 0) {
        *(float4*)(out + rbase)     = make_float4(s[0] + b0, s[1] + b0, s[2] + b0, s[3] + b0);
        *(float4*)(out + rbase + 4) = make_float4(s[4] + b0, s[5] + b0, s[6] + b0, s[7] + b0);
    }
}

extern "C" void kernel_launch(void* const* d_in, const int* in_sizes, int n_in,
                              void* d_out, int out_size, void* d_ws, size_t ws_size,
                              hipStream_t stream) {
    const float* x     = (const float*)d_in[0];
    const float* exu_w = (const float*)d_in[1];
    const float* exu_b = (const float*)d_in[2];
    const float* lin_w = (const float*)d_in[3];
    const float* lin_b = (const float*)d_in[4];
    const float* bias  = (const float*)d_in[5];

    float* out = (float*)d_out;
    float* fnn = out + NB;

    // 2048 waves total: 512 blocks x 4 waves/block, 8 rows/wave = 16384 rows.
    nam_reg<<<dim3(512), dim3(256), 0, stream>>>(
        x, exu_w, exu_b, lin_w, lin_b, bias, out, fnn);
}